// Round 3
// baseline (410.205 us; speedup 1.0000x reference)
//
#include <hip/hip_runtime.h>
#include <hip/hip_cooperative_groups.h>

namespace cg = cooperative_groups;

#define NS 4096
#define NCC 1024
#define DD 64
#define HH2 32
#define NSEQ 32
#define SLEN 256
#define SLOTS 8192
#define LNEPS 1e-3f
#define MAXCH 96      // max sites per 32-slot chunk (mean 16, 20 sigma margin)

// ---------------- K_setup: blocks 0-19 = prep (256 rows each), blocks 20-21 = counting sort ----------------
__global__ void __launch_bounds__(1024) k_setup(
    const float* __restrict__ sites, const float* __restrict__ cons,
    const float* __restrict__ Ws, const float* __restrict__ bs,
    const float* __restrict__ Wc, const float* __restrict__ bc,
    const float* __restrict__ Wd, const float* __restrict__ bd,
    const float* __restrict__ g, const float* __restrict__ Wo,
    float* __restrict__ u, float* __restrict__ A, float* __restrict__ P,
    float* __restrict__ v, float* __restrict__ B, float* __restrict__ Q,
    const int* __restrict__ idxl, const int* __restrict__ idxh,
    int* __restrict__ offl, int* __restrict__ slotl, int* __restrict__ sitel,
    int* __restrict__ offh, int* __restrict__ sloth, int* __restrict__ siteh) {
  __shared__ int cnt[SLOTS];
  __shared__ int wsumI[16];
  int tid = threadIdx.x;
  if (blockIdx.x < 20) {
    // ---- prep: 4 waves/block, one row per thread ----
    if (tid >= 256) return;
    int t = blockIdx.x * 256 + tid;
    if (t >= NS + NCC) return;
    bool isSite = t < NS;
    int row = isSite ? t : t - NS;
    const float* x = isSite ? sites + row * DD : cons + row * DD;
    const float* W1 = isSite ? Ws : Wc;
    const float* b1 = isSite ? bs : bc;
    float s[HH2];
#pragma unroll
    for (int h = 0; h < HH2; h++) s[h] = b1[h];
    for (int k = 0; k < DD; k++) {
      float xv = x[k];
#pragma unroll
      for (int h = 0; h < HH2; h++) s[h] = fmaf(xv, W1[k * HH2 + h], s[h]);
    }
#pragma unroll
    for (int h = 0; h < HH2; h++) s[h] = fmaxf(s[h], 0.0f);
    float hs[HH2];
#pragma unroll
    for (int h = 0; h < HH2; h++) hs[h] = isSite ? 0.0f : bd[h];  // b_d folded into con side
    for (int k = 0; k < HH2; k++) {
      float sv = s[k];
#pragma unroll
      for (int h = 0; h < HH2; h++) hs[h] = fmaf(sv, Wd[k * HH2 + h], hs[h]);
    }
    float mu = 0.f;
#pragma unroll
    for (int h = 0; h < HH2; h++) mu += hs[h];
    mu *= (1.0f / HH2);
    float p = 0.f, a = 0.f;
    float* dst = isSite ? (u + row * HH2) : (v + row * HH2);
#pragma unroll
    for (int h = 0; h < HH2; h++) {
      float uu = hs[h] - mu;
      dst[h] = uu;
      p += uu * uu;
      a = fmaf(uu * g[h], Wo[h], a);
    }
    p *= (1.0f / HH2);
    if (isSite) { A[row] = a; P[row] = p; } else { B[row] = a; Q[row] = p; }
    return;
  }
  // ---- sort (blocks 20,21) ----
  int lane = tid & 63, wv = tid >> 6;
  int pass = blockIdx.x - 20;
  const int* idx = pass ? idxh : idxl;
  int* off = pass ? offh : offl;
  int* slotA = pass ? sloth : slotl;
  int* siteA = pass ? siteh : sitel;
  for (int i2 = tid; i2 < SLOTS; i2 += 1024) cnt[i2] = 0;
  __syncthreads();
  for (int i2 = tid; i2 < NS; i2 += 1024) atomicAdd(&cnt[idx[i2]], 1);
  __syncthreads();
  int base = tid * 8;
  int loc[8]; int sum = 0;
#pragma unroll
  for (int q2 = 0; q2 < 8; q2++) { loc[q2] = sum; sum += cnt[base + q2]; }
  int incl = sum;
#pragma unroll
  for (int o = 1; o < 64; o <<= 1) { int t2 = __shfl_up(incl, o); if (lane >= o) incl += t2; }
  if (lane == 63) wsumI[wv] = incl;
  __syncthreads();
  int wprev = 0;
#pragma unroll
  for (int w = 0; w < 16; w++) { int t3 = wsumI[w]; if (w < wv) wprev += t3; }
  int excl = wprev + (incl - sum);
  __syncthreads();
#pragma unroll
  for (int q2 = 0; q2 < 8; q2++) { int o2 = excl + loc[q2]; off[base + q2] = o2; cnt[base + q2] = o2; }
  if (tid == 0) off[SLOTS] = NS;
  __syncthreads();
  for (int i2 = tid; i2 < NS; i2 += 1024) {
    int sl = idx[i2];
    int pos = atomicAdd(&cnt[sl], 1);
    slotA[pos] = sl; siteA[pos] = i2;
  }
}

// ---------------- K_main: logits -> softmax -> cumsums; 16 rows/block, no max phase, 1 barrier ----------------
// Logits are structurally bounded (|logit| ~< 15): exp() cannot overflow f32;
// normalization makes the result identical to max-shifted softmax.
__global__ void __launch_bounds__(1024) k_main(const float* __restrict__ u,
    const float* __restrict__ A, const float* __restrict__ P,
    const float* __restrict__ v, const float* __restrict__ B, const float* __restrict__ Q,
    const float* __restrict__ lnb, const float* __restrict__ Wo, const float* __restrict__ bo,
    float* __restrict__ M, float* __restrict__ CLp, float* __restrict__ CHp) {
  int j = threadIdx.x;
  int lane = j & 63, wv = j >> 6;
  __shared__ float redB[16 * 16];  // [row][wave] wave sums
  float4 vv[8];
  const float4* vp = (const float4*)(v + j * HH2);
#pragma unroll
  for (int q = 0; q < 8; q++) vv[q] = vp[q];
  float Bj = B[j], Qj = Q[j];
  float C = bo[0];
#pragma unroll
  for (int k = 0; k < HH2; k++) C = fmaf(lnb[k], Wo[k], C);
  int row0 = blockIdx.x * 16;

  float e[16], incl[16];
#pragma unroll
  for (int rr = 0; rr < 16; rr++) {
    int i = row0 + rr;
    const float4* up = (const float4*)(u + i * HH2);
    float dot = 0.f;
#pragma unroll
    for (int q = 0; q < 8; q++) {
      float4 u4 = up[q];
      dot = fmaf(u4.x, vv[q].x, dot);
      dot = fmaf(u4.y, vv[q].y, dot);
      dot = fmaf(u4.z, vv[q].z, dot);
      dot = fmaf(u4.w, vv[q].w, dot);
    }
    float var = P[i] + Qj + dot * 0.0625f;   // P + Q + 2*dot/32
    float lg = rsqrtf(var + LNEPS) * (A[i] + Bj) + C;
    float ee = __expf(lg);
    float ic = ee;
#pragma unroll
    for (int o = 1; o < 64; o <<= 1) { float tt = __shfl_up(ic, o); if (lane >= o) ic += tt; }
    if (lane == 63) redB[rr * 16 + wv] = ic;
    e[rr] = ee; incl[rr] = ic;
  }
  __syncthreads();
#pragma unroll
  for (int rr = 0; rr < 16; rr++) {
    const float4* rb = (const float4*)(redB + rr * 16);
    float4 b0 = rb[0], b1 = rb[1], b2 = rb[2], b3 = rb[3];
    float w_[16] = {b0.x, b0.y, b0.z, b0.w, b1.x, b1.y, b1.z, b1.w,
                    b2.x, b2.y, b2.z, b2.w, b3.x, b3.y, b3.z, b3.w};
    float prev = 0.f, tot = 0.f;
#pragma unroll
    for (int w = 0; w < 16; w++) { tot += w_[w]; if (w < wv) prev += w_[w]; }
    float chE = prev + incl[rr];
    float rd = 1.0f / tot;
    int o_ = (row0 + rr) * NCC + j;
    M[o_] = e[rr] * rd;                    // softmax (to d_out)
    CHp[o_] = chE * rd;                    // forward cumsum
    CLp[o_] = (tot - chE + e[rr]) * rd;    // reverse cumsum
  }
}

// ---------------- K_mega: band scan + chunk prefix + final multiply in ONE cooperative kernel ----------------
// Phase 1: 2048 (band,seq,chunk,coltile) tiles over 1024 blocks (2 rounds) — chunk-local
//          exclusive cumprod written in place over CLp/CHp, chunk totals to TT.
// Phase 2: exclusive product of the 8 chunk totals per (band,seq,col)  [blocks 0..255]
// Phase 3: out = M * EL*PL * EH*PH — streaming float4, CLp/CHp/TT L2-hot from phase 1.
// __launch_bounds__(256,4): VGPR <= 128 -> guaranteed 4 blocks/CU -> 1024 blocks always co-resident.
__global__ void __launch_bounds__(256, 4) k_mega(
    float* __restrict__ CLp, float* __restrict__ CHp,
    const int* __restrict__ offl, const int* __restrict__ slotl, const int* __restrict__ sitel,
    const int* __restrict__ offh, const int* __restrict__ sloth, const int* __restrict__ siteh,
    float* __restrict__ TT, float* __restrict__ out,
    const int* __restrict__ idxl, const int* __restrict__ idxh) {
  cg::grid_group grid = cg::this_grid();
  int b = blockIdx.x;
  int tid = threadIdx.x;
  __shared__ int ss[MAXCH];
  __shared__ int sl[MAXCH];
  // ---- phase 1 ----
  for (int rnd = 0; rnd < 2; rnd++) {
    int t = b + rnd * 1024;             // tile id 0..2047
    int coltile = t & 3;
    int chunk = (t >> 2) & 7;
    int band = (t >> 5) & 1;
    int seq = t >> 6;
    const int* off = band ? offh : offl;
    const int* slA = band ? sloth : slotl;
    const int* siA = band ? siteh : sitel;
    float* Cb = band ? CHp : CLp;
    int j = coltile * 256 + tid;
    int slot0 = seq * SLEN + chunk * 32;
    int s0 = off[slot0];
    int n = off[slot0 + 32] - s0;
    size_t trow = ((size_t)band * 256 + seq * 8 + chunk) * NCC + j;
    __syncthreads();                    // protect LDS reuse across rounds (uniform: n is block-uniform)
    if (n > MAXCH) n = MAXCH;           // statistically impossible (20 sigma); avoid OOB
    for (int i = tid; i < n; i += 256) { ss[i] = siA[s0 + i]; sl[i] = slA[s0 + i]; }
    __syncthreads();
    if (n <= 0) { TT[trow] = 1.0f; continue; }   // empty chunk: product of 32 unit factors

    const int T = 32;  // covers n<=32; all loads issued before any store (in-place safe)
    float buf[T];
#pragma unroll
    for (int k = 0; k < T; k++) {
      int kk = k < n ? k : n - 1;
      buf[k] = Cb[(size_t)ss[kk] * NCC + j];
    }
    float r = 1.f, z = 0.f;
    int prev = -1;
#pragma unroll
    for (int k = 0; k < T; k++) {
      if (k < n) {
        float cv = buf[k];
        int slot = sl[k];
        if (slot != prev) {             // uniform branch (sl in LDS, same for all lanes)
          if (prev >= 0) { r *= fmaxf(1.f - z, 0.f); z = 0.f; }
          prev = slot;
        }
        Cb[(size_t)ss[k] * NCC + j] = r;  // chunk-local exclusive cumprod
        z += cv;
      }
    }
    for (int k = T; k < n; k++) {       // rare tail (n > 32)
      float cv = Cb[(size_t)ss[k] * NCC + j];
      int slot = sl[k];
      if (slot != prev) {
        if (prev >= 0) { r *= fmaxf(1.f - z, 0.f); z = 0.f; }
        prev = slot;
      }
      Cb[(size_t)ss[k] * NCC + j] = r;
      z += cv;
    }
    r *= fmaxf(1.f - z, 0.f);           // close the last occupied slot
    TT[trow] = r;                       // chunk total (empty trailing slots contribute 1)
  }
  grid.sync();
  // ---- phase 2: prefix over 8 chunk totals; one col per thread, blocks 0..255 ----
  if (b < 256) {
    int group = b >> 2;                 // band*32+seq, 0..63 (TT row base = group*8)
    int col = (b & 3) * 256 + tid;
    float* base = TT + (size_t)group * 8 * NCC + col;
    float t0[8];
#pragma unroll
    for (int c = 0; c < 8; c++) t0[c] = base[(size_t)c * NCC];
    float p = 1.f;
#pragma unroll
    for (int c = 0; c < 8; c++) { base[(size_t)c * NCC] = p; p *= t0[c]; }
  }
  grid.sync();
  // ---- phase 3: final multiply, 4 site-rows per block ----
  {
    int jj = tid * 4;
    const float* TTH = TT + (size_t)256 * NCC;
#pragma unroll
    for (int k = 0; k < 4; k++) {
      int s = b * 4 + k;
      size_t bofs = (size_t)s * NCC + jj;
      float4 m  = *(const float4*)(out + bofs);
      float4 el = *(const float4*)(CLp + bofs);
      float4 eh = *(const float4*)(CHp + bofs);
      float4 pl = *(const float4*)(TT  + (size_t)(idxl[s] >> 5) * NCC + jj);
      float4 ph = *(const float4*)(TTH + (size_t)(idxh[s] >> 5) * NCC + jj);
      float4 o;
      o.x = m.x * el.x * pl.x * eh.x * ph.x;
      o.y = m.y * el.y * pl.y * eh.y * ph.y;
      o.z = m.z * el.z * pl.z * eh.z * ph.z;
      o.w = m.w * el.w * pl.w * eh.w * ph.w;
      *(float4*)(out + bofs) = o;
    }
  }
}

// ---------------- Fallback path (identical to the round-2 passing kernels) ----------------
__global__ void __launch_bounds__(256) k_band(
    float* __restrict__ CLp, float* __restrict__ CHp,
    const int* __restrict__ offl, const int* __restrict__ slotl, const int* __restrict__ sitel,
    const int* __restrict__ offh, const int* __restrict__ sloth, const int* __restrict__ siteh,
    float* __restrict__ TT) {
  int band = blockIdx.y >> 3;
  int chunk = blockIdx.y & 7;
  int seq = blockIdx.z;
  int j = blockIdx.x * 256 + threadIdx.x;
  const int* off = band ? offh : offl;
  const int* slA = band ? sloth : slotl;
  const int* siA = band ? siteh : sitel;
  float* C = band ? CHp : CLp;
  int slot0 = seq * SLEN + chunk * 32;
  int s0 = off[slot0];
  int n = off[slot0 + 32] - s0;
  size_t trow = ((size_t)band * 256 + seq * 8 + chunk) * NCC + j;
  if (n <= 0) { TT[trow] = 1.0f; return; }
  if (n > MAXCH) n = MAXCH;
  __shared__ int ss[MAXCH];
  __shared__ int sl[MAXCH];
  for (int i = threadIdx.x; i < n; i += 256) { ss[i] = siA[s0 + i]; sl[i] = slA[s0 + i]; }
  __syncthreads();
  const int T = 32;
  float buf[T];
#pragma unroll
  for (int k = 0; k < T; k++) {
    int kk = k < n ? k : n - 1;
    buf[k] = C[(size_t)ss[kk] * NCC + j];
  }
  float r = 1.f, z = 0.f;
  int prev = -1;
#pragma unroll
  for (int k = 0; k < T; k++) {
    if (k < n) {
      float cv = buf[k];
      int slot = sl[k];
      if (slot != prev) {
        if (prev >= 0) { r *= fmaxf(1.f - z, 0.f); z = 0.f; }
        prev = slot;
      }
      C[(size_t)ss[k] * NCC + j] = r;
      z += cv;
    }
  }
  for (int k = T; k < n; k++) {
    float cv = C[(size_t)ss[k] * NCC + j];
    int slot = sl[k];
    if (slot != prev) {
      if (prev >= 0) { r *= fmaxf(1.f - z, 0.f); z = 0.f; }
      prev = slot;
    }
    C[(size_t)ss[k] * NCC + j] = r;
    z += cv;
  }
  r *= fmaxf(1.f - z, 0.f);
  TT[trow] = r;
}

__global__ void __launch_bounds__(1024) k_prefix(float* __restrict__ TT) {
  int b = blockIdx.x;
  int j = threadIdx.x;
  float* base = TT + (size_t)b * 8 * NCC + j;
  float t[8];
#pragma unroll
  for (int c = 0; c < 8; c++) t[c] = base[(size_t)c * NCC];
  float p = 1.f;
#pragma unroll
  for (int c = 0; c < 8; c++) { base[(size_t)c * NCC] = p; p *= t[c]; }
}

__global__ void __launch_bounds__(256) k_final(
    float* __restrict__ out, const float* __restrict__ ELr, const float* __restrict__ EHr,
    const float* __restrict__ TT, const int* __restrict__ idxl, const int* __restrict__ idxh) {
  int j = threadIdx.x * 4;
  int s0 = blockIdx.x * 8;
  const float* TTH = TT + (size_t)256 * NCC;
#pragma unroll 4
  for (int k = 0; k < 8; k++) {
    int s = s0 + k;
    size_t bofs = (size_t)s * NCC + j;
    float4 m  = *(const float4*)(out + bofs);
    float4 el = *(const float4*)(ELr + bofs);
    float4 eh = *(const float4*)(EHr + bofs);
    float4 pl = *(const float4*)(TT  + (size_t)(idxl[s] >> 5) * NCC + j);
    float4 ph = *(const float4*)(TTH + (size_t)(idxh[s] >> 5) * NCC + j);
    float4 o;
    o.x = m.x * el.x * pl.x * eh.x * ph.x;
    o.y = m.y * el.y * pl.y * eh.y * ph.y;
    o.z = m.z * el.z * pl.z * eh.z * ph.z;
    o.w = m.w * el.w * pl.w * eh.w * ph.w;
    *(float4*)(out + bofs) = o;
  }
}

extern "C" void kernel_launch(void* const* d_in, const int* in_sizes, int n_in,
                              void* d_out, int out_size, void* d_ws, size_t ws_size,
                              hipStream_t stream) {
  const float* sites = (const float*)d_in[0];
  const float* cons  = (const float*)d_in[1];
  const int* idxl = (const int*)d_in[2];
  const int* idxh = (const int*)d_in[3];
  const float* Ws = (const float*)d_in[4];
  const float* bs = (const float*)d_in[5];
  const float* Wc = (const float*)d_in[6];
  const float* bc = (const float*)d_in[7];
  const float* Wd = (const float*)d_in[8];
  const float* bd = (const float*)d_in[9];
  const float* lng = (const float*)d_in[10];
  const float* lnb = (const float*)d_in[11];
  const float* Wo = (const float*)d_in[12];
  const float* bo = (const float*)d_in[13];

  char* wsb = (char*)d_ws;
  size_t o = 0;
  auto alloc = [&](size_t bytes) { char* p = wsb + o; o += (bytes + 15) & ~(size_t)15; return p; };
  float* u   = (float*)alloc((size_t)NS * HH2 * 4);
  float* A   = (float*)alloc((size_t)NS * 4);
  float* P   = (float*)alloc((size_t)NS * 4);
  float* v   = (float*)alloc((size_t)NCC * HH2 * 4);
  float* B   = (float*)alloc((size_t)NCC * 4);
  float* Q   = (float*)alloc((size_t)NCC * 4);
  float* CLp = (float*)alloc((size_t)NS * NCC * 4);
  float* CHp = (float*)alloc((size_t)NS * NCC * 4);
  float* TT  = (float*)alloc((size_t)2 * 256 * NCC * 4);   // [band][seq*8+chunk][col]
  int* offl  = (int*)alloc((SLOTS + 1) * 4);
  int* slotl = (int*)alloc(NS * 4);
  int* sitel = (int*)alloc(NS * 4);
  int* offh  = (int*)alloc((SLOTS + 1) * 4);
  int* sloth = (int*)alloc(NS * 4);
  int* siteh = (int*)alloc(NS * 4);

  k_setup<<<22, 1024, 0, stream>>>(sites, cons, Ws, bs, Wc, bc, Wd, bd, lng, Wo,
                                   u, A, P, v, B, Q,
                                   idxl, idxh, offl, slotl, sitel, offh, sloth, siteh);
  k_main<<<NS / 16, 1024, 0, stream>>>(u, A, P, v, B, Q, lnb, Wo, bo,
                                       (float*)d_out, CLp, CHp);

  float* out_f = (float*)d_out;
  void* args[] = { &CLp, &CHp,
                   (void*)&offl, (void*)&slotl, (void*)&sitel,
                   (void*)&offh, (void*)&sloth, (void*)&siteh,
                   &TT, &out_f, (void*)&idxl, (void*)&idxh };
  hipError_t ce = hipLaunchCooperativeKernel((const void*)k_mega, dim3(1024), dim3(256),
                                             args, 0, stream);
  if (ce != hipSuccess) {
    // capture-time failure of cooperative launch: fall back to the proven 3-kernel path
    k_band<<<dim3(4, 16, 32), 256, 0, stream>>>(CLp, CHp,
                                                offl, slotl, sitel, offh, sloth, siteh, TT);
    k_prefix<<<64, 1024, 0, stream>>>(TT);
    k_final<<<NS / 8, 256, 0, stream>>>((float*)d_out, CLp, CHp, TT, idxl, idxh);
  }
}

// Round 4
// 164.128 us; speedup vs baseline: 2.4993x; 2.4993x over previous
//
#include <hip/hip_runtime.h>

#define NS 4096
#define NCC 1024
#define DD 64
#define HH2 32
#define NSEQ 32
#define SLEN 256
#define SLOTS 8192
#define LNEPS 1e-3f
#define MAXCH 96      // max sites per 32-slot chunk (mean 16, 20 sigma margin)

// ---------------- K_setup: blocks 0-19 = prep (256 rows each), blocks 20-21 = counting sort ----------------
__global__ void __launch_bounds__(1024) k_setup(
    const float* __restrict__ sites, const float* __restrict__ cons,
    const float* __restrict__ Ws, const float* __restrict__ bs,
    const float* __restrict__ Wc, const float* __restrict__ bc,
    const float* __restrict__ Wd, const float* __restrict__ bd,
    const float* __restrict__ g, const float* __restrict__ Wo,
    float* __restrict__ u, float* __restrict__ A, float* __restrict__ P,
    float* __restrict__ v, float* __restrict__ B, float* __restrict__ Q,
    const int* __restrict__ idxl, const int* __restrict__ idxh,
    int* __restrict__ offl, int* __restrict__ slotl, int* __restrict__ sitel,
    int* __restrict__ offh, int* __restrict__ sloth, int* __restrict__ siteh) {
  __shared__ int cnt[SLOTS];
  __shared__ int wsumI[16];
  int tid = threadIdx.x;
  if (blockIdx.x < 20) {
    // ---- prep: 4 waves/block, one row per thread ----
    if (tid >= 256) return;
    int t = blockIdx.x * 256 + tid;
    if (t >= NS + NCC) return;
    bool isSite = t < NS;
    int row = isSite ? t : t - NS;
    const float* x = isSite ? sites + row * DD : cons + row * DD;
    const float* W1 = isSite ? Ws : Wc;
    const float* b1 = isSite ? bs : bc;
    float s[HH2];
#pragma unroll
    for (int h = 0; h < HH2; h++) s[h] = b1[h];
    for (int k = 0; k < DD; k++) {
      float xv = x[k];
#pragma unroll
      for (int h = 0; h < HH2; h++) s[h] = fmaf(xv, W1[k * HH2 + h], s[h]);
    }
#pragma unroll
    for (int h = 0; h < HH2; h++) s[h] = fmaxf(s[h], 0.0f);
    float hs[HH2];
#pragma unroll
    for (int h = 0; h < HH2; h++) hs[h] = isSite ? 0.0f : bd[h];  // b_d folded into con side
    for (int k = 0; k < HH2; k++) {
      float sv = s[k];
#pragma unroll
      for (int h = 0; h < HH2; h++) hs[h] = fmaf(sv, Wd[k * HH2 + h], hs[h]);
    }
    float mu = 0.f;
#pragma unroll
    for (int h = 0; h < HH2; h++) mu += hs[h];
    mu *= (1.0f / HH2);
    float p = 0.f, a = 0.f;
    float* dst = isSite ? (u + row * HH2) : (v + row * HH2);
#pragma unroll
    for (int h = 0; h < HH2; h++) {
      float uu = hs[h] - mu;
      dst[h] = uu;
      p += uu * uu;
      a = fmaf(uu * g[h], Wo[h], a);
    }
    p *= (1.0f / HH2);
    if (isSite) { A[row] = a; P[row] = p; } else { B[row] = a; Q[row] = p; }
    return;
  }
  // ---- sort (blocks 20,21) ----
  int lane = tid & 63, wv = tid >> 6;
  int pass = blockIdx.x - 20;
  const int* idx = pass ? idxh : idxl;
  int* off = pass ? offh : offl;
  int* slotA = pass ? sloth : slotl;
  int* siteA = pass ? siteh : sitel;
  for (int i2 = tid; i2 < SLOTS; i2 += 1024) cnt[i2] = 0;
  __syncthreads();
  for (int i2 = tid; i2 < NS; i2 += 1024) atomicAdd(&cnt[idx[i2]], 1);
  __syncthreads();
  int base = tid * 8;
  int loc[8]; int sum = 0;
#pragma unroll
  for (int q2 = 0; q2 < 8; q2++) { loc[q2] = sum; sum += cnt[base + q2]; }
  int incl = sum;
#pragma unroll
  for (int o = 1; o < 64; o <<= 1) { int t2 = __shfl_up(incl, o); if (lane >= o) incl += t2; }
  if (lane == 63) wsumI[wv] = incl;
  __syncthreads();
  int wprev = 0;
#pragma unroll
  for (int w = 0; w < 16; w++) { int t3 = wsumI[w]; if (w < wv) wprev += t3; }
  int excl = wprev + (incl - sum);
  __syncthreads();
#pragma unroll
  for (int q2 = 0; q2 < 8; q2++) { int o2 = excl + loc[q2]; off[base + q2] = o2; cnt[base + q2] = o2; }
  if (tid == 0) off[SLOTS] = NS;
  __syncthreads();
  for (int i2 = tid; i2 < NS; i2 += 1024) {
    int sl = idx[i2];
    int pos = atomicAdd(&cnt[sl], 1);
    slotA[pos] = sl; siteA[pos] = i2;
  }
}

// ---------------- K_main: logits -> softmax -> forward cumsum CHp ONLY ----------------
// Everything downstream derives from CHp: M[j] = CH[j]-CH[j-1], CL[j] = 1-CH[j-1], CH[j] = CH[j].
// (M rows are softmax-normalized so the row total is exactly 1.0 by construction of chE_last.)
__global__ void __launch_bounds__(1024) k_main(const float* __restrict__ u,
    const float* __restrict__ A, const float* __restrict__ P,
    const float* __restrict__ v, const float* __restrict__ B, const float* __restrict__ Q,
    const float* __restrict__ lnb, const float* __restrict__ Wo, const float* __restrict__ bo,
    float* __restrict__ CHp) {
  int j = threadIdx.x;
  int lane = j & 63, wv = j >> 6;
  __shared__ float redB[16 * 16];  // [row][wave] wave sums
  float4 vv[8];
  const float4* vp = (const float4*)(v + j * HH2);
#pragma unroll
  for (int q = 0; q < 8; q++) vv[q] = vp[q];
  float Bj = B[j], Qj = Q[j];
  float C = bo[0];
#pragma unroll
  for (int k = 0; k < HH2; k++) C = fmaf(lnb[k], Wo[k], C);
  int row0 = blockIdx.x * 16;

  float e[16], incl[16];
#pragma unroll
  for (int rr = 0; rr < 16; rr++) {
    int i = row0 + rr;
    const float4* up = (const float4*)(u + i * HH2);
    float dot = 0.f;
#pragma unroll
    for (int q = 0; q < 8; q++) {
      float4 u4 = up[q];
      dot = fmaf(u4.x, vv[q].x, dot);
      dot = fmaf(u4.y, vv[q].y, dot);
      dot = fmaf(u4.z, vv[q].z, dot);
      dot = fmaf(u4.w, vv[q].w, dot);
    }
    float var = P[i] + Qj + dot * 0.0625f;   // P + Q + 2*dot/32
    float lg = rsqrtf(var + LNEPS) * (A[i] + Bj) + C;
    float ee = __expf(lg);
    float ic = ee;
#pragma unroll
    for (int o = 1; o < 64; o <<= 1) { float tt = __shfl_up(ic, o); if (lane >= o) ic += tt; }
    if (lane == 63) redB[rr * 16 + wv] = ic;
    e[rr] = ee; incl[rr] = ic;
  }
  __syncthreads();
#pragma unroll
  for (int rr = 0; rr < 16; rr++) {
    const float4* rb = (const float4*)(redB + rr * 16);
    float4 b0 = rb[0], b1 = rb[1], b2 = rb[2], b3 = rb[3];
    float w_[16] = {b0.x, b0.y, b0.z, b0.w, b1.x, b1.y, b1.z, b1.w,
                    b2.x, b2.y, b2.z, b2.w, b3.x, b3.y, b3.z, b3.w};
    float prev = 0.f, tot = 0.f;
#pragma unroll
    for (int w = 0; w < 16; w++) { tot += w_[w]; if (w < wv) prev += w_[w]; }
    float chE = prev + incl[rr];
    float rd = 1.0f / tot;
    CHp[(row0 + rr) * NCC + j] = chE * rd;   // forward inclusive cumsum (last col == 1.0 exactly)
  }
}

// ---------------- K_bandL: lower band; reads CHp, PURE-WRITES out = M * EL_chunklocal ----------------
// grid (2 coltiles, 8 chunks, 32 seqs), 256 thr, float2/thread. cv_L[j] = 1 - CH[j-1]; M[j] = CH[j]-CH[j-1].
__global__ void __launch_bounds__(256) k_bandL(
    const float* __restrict__ CHp,
    const int* __restrict__ offl, const int* __restrict__ slotl, const int* __restrict__ sitel,
    float* __restrict__ out, float* __restrict__ TT) {
  int chunk = blockIdx.y, seq = blockIdx.z;
  int j0 = blockIdx.x * 512 + threadIdx.x * 2;
  int slot0 = seq * SLEN + chunk * 32;
  int s0 = offl[slot0];
  int n = offl[slot0 + 32] - s0;
  size_t trow = (size_t)(seq * 8 + chunk) * NCC + j0;
  if (n <= 0) { *(float2*)(TT + trow) = make_float2(1.f, 1.f); return; }  // 32 unit factors
  if (n > MAXCH) n = MAXCH;           // statistically impossible (20 sigma); avoid OOB
  __shared__ int ss[MAXCH];
  __shared__ int sl[MAXCH];
  for (int i = threadIdx.x; i < n; i += 256) { ss[i] = sitel[s0 + i]; sl[i] = slotl[s0 + i]; }
  __syncthreads();

  const int T = 32;                    // covers n<=32; all loads issued before any store
  float2 ch[T]; float cm[T];
#pragma unroll
  for (int k = 0; k < T; k++) {
    int kk = k < n ? k : n - 1;
    const float* rp = CHp + (size_t)ss[kk] * NCC + j0;
    ch[k] = *(const float2*)rp;
    cm[k] = (j0 == 0) ? 0.f : rp[-1];  // same cacheline as ch[k].x
  }
  float2 r = make_float2(1.f, 1.f), z = make_float2(0.f, 0.f);
  int prev = -1;
#pragma unroll
  for (int k = 0; k < T; k++) {
    if (k < n) {
      int slot = sl[k];
      if (slot != prev) {              // uniform branch (sl in LDS, same for all lanes)
        if (prev >= 0) {
          r.x *= fmaxf(1.f - z.x, 0.f); r.y *= fmaxf(1.f - z.y, 0.f);
          z = make_float2(0.f, 0.f);
        }
        prev = slot;
      }
      float2 o;
      o.x = (ch[k].x - cm[k]) * r.x;   // M[j0]   * EL
      o.y = (ch[k].y - ch[k].x) * r.y; // M[j0+1] * EL
      *(float2*)(out + (size_t)ss[k] * NCC + j0) = o;
      z.x += 1.f - cm[k];              // cv_L[j0]   = 1 - CH[j0-1]
      z.y += 1.f - ch[k].x;            // cv_L[j0+1] = 1 - CH[j0]
    }
  }
  for (int k = T; k < n; k++) {        // rare tail (n > 32)
    const float* rp = CHp + (size_t)ss[k] * NCC + j0;
    float2 c2 = *(const float2*)rp;
    float cmv = (j0 == 0) ? 0.f : rp[-1];
    int slot = sl[k];
    if (slot != prev) {
      if (prev >= 0) {
        r.x *= fmaxf(1.f - z.x, 0.f); r.y *= fmaxf(1.f - z.y, 0.f);
        z = make_float2(0.f, 0.f);
      }
      prev = slot;
    }
    float2 o;
    o.x = (c2.x - cmv) * r.x;
    o.y = (c2.y - c2.x) * r.y;
    *(float2*)(out + (size_t)ss[k] * NCC + j0) = o;
    z.x += 1.f - cmv; z.y += 1.f - c2.x;
  }
  r.x *= fmaxf(1.f - z.x, 0.f); r.y *= fmaxf(1.f - z.y, 0.f);  // close last occupied slot
  *(float2*)(TT + trow) = r;
}

// ---------------- K_bandH: higher band; reads CHp (L2-hot) + out (L2-hot), in-place out *= EH ----------------
// cv_H[j] = CH[j]. All out-loads prefetched before any store (distinct rows; compiler-visible safe).
__global__ void __launch_bounds__(256) k_bandH(
    const float* __restrict__ CHp,
    const int* __restrict__ offh, const int* __restrict__ sloth, const int* __restrict__ siteh,
    float* __restrict__ out, float* __restrict__ TT) {
  int chunk = blockIdx.y, seq = blockIdx.z;
  int j0 = blockIdx.x * 512 + threadIdx.x * 2;
  int slot0 = seq * SLEN + chunk * 32;
  int s0 = offh[slot0];
  int n = offh[slot0 + 32] - s0;
  size_t trow = (size_t)(256 + seq * 8 + chunk) * NCC + j0;
  if (n <= 0) { *(float2*)(TT + trow) = make_float2(1.f, 1.f); return; }
  if (n > MAXCH) n = MAXCH;
  __shared__ int ss[MAXCH];
  __shared__ int sl[MAXCH];
  for (int i = threadIdx.x; i < n; i += 256) { ss[i] = siteh[s0 + i]; sl[i] = sloth[s0 + i]; }
  __syncthreads();

  const int T = 32;
  float2 ch[T], mo[T];
#pragma unroll
  for (int k = 0; k < T; k++) {
    int kk = k < n ? k : n - 1;
    ch[k] = *(const float2*)(CHp + (size_t)ss[kk] * NCC + j0);
    mo[k] = *(const float2*)(out + (size_t)ss[kk] * NCC + j0);
  }
  float2 r = make_float2(1.f, 1.f), z = make_float2(0.f, 0.f);
  int prev = -1;
#pragma unroll
  for (int k = 0; k < T; k++) {
    if (k < n) {
      int slot = sl[k];
      if (slot != prev) {
        if (prev >= 0) {
          r.x *= fmaxf(1.f - z.x, 0.f); r.y *= fmaxf(1.f - z.y, 0.f);
          z = make_float2(0.f, 0.f);
        }
        prev = slot;
      }
      float2 o;
      o.x = mo[k].x * r.x;
      o.y = mo[k].y * r.y;
      *(float2*)(out + (size_t)ss[k] * NCC + j0) = o;
      z.x += ch[k].x;                  // cv_H[j0]   = CH[j0]
      z.y += ch[k].y;                  // cv_H[j0+1] = CH[j0+1]
    }
  }
  for (int k = T; k < n; k++) {        // rare tail
    float2 c2 = *(const float2*)(CHp + (size_t)ss[k] * NCC + j0);
    float2 m2 = *(const float2*)(out + (size_t)ss[k] * NCC + j0);
    int slot = sl[k];
    if (slot != prev) {
      if (prev >= 0) {
        r.x *= fmaxf(1.f - z.x, 0.f); r.y *= fmaxf(1.f - z.y, 0.f);
        z = make_float2(0.f, 0.f);
      }
      prev = slot;
    }
    float2 o; o.x = m2.x * r.x; o.y = m2.y * r.y;
    *(float2*)(out + (size_t)ss[k] * NCC + j0) = o;
    z.x += c2.x; z.y += c2.y;
  }
  r.x *= fmaxf(1.f - z.x, 0.f); r.y *= fmaxf(1.f - z.y, 0.f);
  *(float2*)(TT + trow) = r;
}

// ---------------- K_prefix: exclusive product over the 8 chunk totals per (band, seq, col) ----------------
__global__ void __launch_bounds__(1024) k_prefix(float* __restrict__ TT) {
  int b = blockIdx.x;                  // band*32 + seq, 0..63
  int j = threadIdx.x;
  float* base = TT + (size_t)b * 8 * NCC + j;
  float t[8];
#pragma unroll
  for (int c = 0; c < 8; c++) t[c] = base[(size_t)c * NCC];
  float p = 1.f;
#pragma unroll
  for (int c = 0; c < 8; c++) { base[(size_t)c * NCC] = p; p *= t[c]; }
}

// ---------------- K_final: out *= PL * PH — streaming float4; TT (4 MiB) L2-resident ----------------
__global__ void __launch_bounds__(256) k_final(
    float* __restrict__ out, const float* __restrict__ TT,
    const int* __restrict__ idxl, const int* __restrict__ idxh) {
  int j = threadIdx.x * 4;
  int s0 = blockIdx.x * 8;
  const float* TTH = TT + (size_t)256 * NCC;
#pragma unroll 4
  for (int k = 0; k < 8; k++) {
    int s = s0 + k;
    size_t bofs = (size_t)s * NCC + j;
    float4 m  = *(const float4*)(out + bofs);
    float4 pl = *(const float4*)(TT  + (size_t)(idxl[s] >> 5) * NCC + j);
    float4 ph = *(const float4*)(TTH + (size_t)(idxh[s] >> 5) * NCC + j);
    float4 o;
    o.x = m.x * pl.x * ph.x;
    o.y = m.y * pl.y * ph.y;
    o.z = m.z * pl.z * ph.z;
    o.w = m.w * pl.w * ph.w;
    *(float4*)(out + bofs) = o;
  }
}

extern "C" void kernel_launch(void* const* d_in, const int* in_sizes, int n_in,
                              void* d_out, int out_size, void* d_ws, size_t ws_size,
                              hipStream_t stream) {
  const float* sites = (const float*)d_in[0];
  const float* cons  = (const float*)d_in[1];
  const int* idxl = (const int*)d_in[2];
  const int* idxh = (const int*)d_in[3];
  const float* Ws = (const float*)d_in[4];
  const float* bs = (const float*)d_in[5];
  const float* Wc = (const float*)d_in[6];
  const float* bc = (const float*)d_in[7];
  const float* Wd = (const float*)d_in[8];
  const float* bd = (const float*)d_in[9];
  const float* lng = (const float*)d_in[10];
  const float* lnb = (const float*)d_in[11];
  const float* Wo = (const float*)d_in[12];
  const float* bo = (const float*)d_in[13];

  char* wsb = (char*)d_ws;
  size_t o = 0;
  auto alloc = [&](size_t bytes) { char* p = wsb + o; o += (bytes + 15) & ~(size_t)15; return p; };
  float* u   = (float*)alloc((size_t)NS * HH2 * 4);
  float* A   = (float*)alloc((size_t)NS * 4);
  float* P   = (float*)alloc((size_t)NS * 4);
  float* v   = (float*)alloc((size_t)NCC * HH2 * 4);
  float* B   = (float*)alloc((size_t)NCC * 4);
  float* Q   = (float*)alloc((size_t)NCC * 4);
  float* CHp = (float*)alloc((size_t)NS * NCC * 4);
  float* TT  = (float*)alloc((size_t)2 * 256 * NCC * 4);   // [band][seq*8+chunk][col]
  int* offl  = (int*)alloc((SLOTS + 1) * 4);
  int* slotl = (int*)alloc(NS * 4);
  int* sitel = (int*)alloc(NS * 4);
  int* offh  = (int*)alloc((SLOTS + 1) * 4);
  int* sloth = (int*)alloc(NS * 4);
  int* siteh = (int*)alloc(NS * 4);

  k_setup<<<22, 1024, 0, stream>>>(sites, cons, Ws, bs, Wc, bc, Wd, bd, lng, Wo,
                                   u, A, P, v, B, Q,
                                   idxl, idxh, offl, slotl, sitel, offh, sloth, siteh);
  k_main<<<NS / 16, 1024, 0, stream>>>(u, A, P, v, B, Q, lnb, Wo, bo, CHp);
  k_bandL<<<dim3(2, 8, NSEQ), 256, 0, stream>>>(CHp, offl, slotl, sitel, (float*)d_out, TT);
  k_bandH<<<dim3(2, 8, NSEQ), 256, 0, stream>>>(CHp, offh, sloth, siteh, (float*)d_out, TT);
  k_prefix<<<64, 1024, 0, stream>>>(TT);
  k_final<<<NS / 8, 256, 0, stream>>>((float*)d_out, TT, idxl, idxh);
}

// Round 5
// 160.180 us; speedup vs baseline: 2.5609x; 1.0246x over previous
//
#include <hip/hip_runtime.h>

#define NS 4096
#define NCC 1024
#define DD 64
#define HH2 32
#define NSEQ 32
#define SLEN 256
#define SLOTS 8192
#define LNEPS 1e-3f
#define MAXCH 96      // max sites per 32-slot chunk (mean 16; real-data max confirmed < 96 by R2/R4 passes)

// ---------------- K_setup: blocks 0-19 = prep (256 rows each), blocks 20-21 = counting sort ----------------
__global__ void __launch_bounds__(1024) k_setup(
    const float* __restrict__ sites, const float* __restrict__ cons,
    const float* __restrict__ Ws, const float* __restrict__ bs,
    const float* __restrict__ Wc, const float* __restrict__ bc,
    const float* __restrict__ Wd, const float* __restrict__ bd,
    const float* __restrict__ g, const float* __restrict__ Wo,
    float* __restrict__ u, float* __restrict__ A, float* __restrict__ P,
    float* __restrict__ v, float* __restrict__ B, float* __restrict__ Q,
    const int* __restrict__ idxl, const int* __restrict__ idxh,
    int* __restrict__ offl, int* __restrict__ slotl, int* __restrict__ sitel,
    int* __restrict__ offh, int* __restrict__ sloth, int* __restrict__ siteh) {
  __shared__ int cnt[SLOTS];
  __shared__ int wsumI[16];
  int tid = threadIdx.x;
  if (blockIdx.x < 20) {
    // ---- prep: 4 waves/block, one row per thread ----
    if (tid >= 256) return;
    int t = blockIdx.x * 256 + tid;
    if (t >= NS + NCC) return;
    bool isSite = t < NS;
    int row = isSite ? t : t - NS;
    const float* x = isSite ? sites + row * DD : cons + row * DD;
    const float* W1 = isSite ? Ws : Wc;
    const float* b1 = isSite ? bs : bc;
    float s[HH2];
#pragma unroll
    for (int h = 0; h < HH2; h++) s[h] = b1[h];
    for (int k = 0; k < DD; k++) {
      float xv = x[k];
#pragma unroll
      for (int h = 0; h < HH2; h++) s[h] = fmaf(xv, W1[k * HH2 + h], s[h]);
    }
#pragma unroll
    for (int h = 0; h < HH2; h++) s[h] = fmaxf(s[h], 0.0f);
    float hs[HH2];
#pragma unroll
    for (int h = 0; h < HH2; h++) hs[h] = isSite ? 0.0f : bd[h];  // b_d folded into con side
    for (int k = 0; k < HH2; k++) {
      float sv = s[k];
#pragma unroll
      for (int h = 0; h < HH2; h++) hs[h] = fmaf(sv, Wd[k * HH2 + h], hs[h]);
    }
    float mu = 0.f;
#pragma unroll
    for (int h = 0; h < HH2; h++) mu += hs[h];
    mu *= (1.0f / HH2);
    float p = 0.f, a = 0.f;
    float* dst = isSite ? (u + row * HH2) : (v + row * HH2);
#pragma unroll
    for (int h = 0; h < HH2; h++) {
      float uu = hs[h] - mu;
      dst[h] = uu;
      p += uu * uu;
      a = fmaf(uu * g[h], Wo[h], a);
    }
    p *= (1.0f / HH2);
    if (isSite) { A[row] = a; P[row] = p; } else { B[row] = a; Q[row] = p; }
    return;
  }
  // ---- sort (blocks 20,21) ----
  int lane = tid & 63, wv = tid >> 6;
  int pass = blockIdx.x - 20;
  const int* idx = pass ? idxh : idxl;
  int* off = pass ? offh : offl;
  int* slotA = pass ? sloth : slotl;
  int* siteA = pass ? siteh : sitel;
  for (int i2 = tid; i2 < SLOTS; i2 += 1024) cnt[i2] = 0;
  __syncthreads();
  for (int i2 = tid; i2 < NS; i2 += 1024) atomicAdd(&cnt[idx[i2]], 1);
  __syncthreads();
  int base = tid * 8;
  int loc[8]; int sum = 0;
#pragma unroll
  for (int q2 = 0; q2 < 8; q2++) { loc[q2] = sum; sum += cnt[base + q2]; }
  int incl = sum;
#pragma unroll
  for (int o = 1; o < 64; o <<= 1) { int t2 = __shfl_up(incl, o); if (lane >= o) incl += t2; }
  if (lane == 63) wsumI[wv] = incl;
  __syncthreads();
  int wprev = 0;
#pragma unroll
  for (int w = 0; w < 16; w++) { int t3 = wsumI[w]; if (w < wv) wprev += t3; }
  int excl = wprev + (incl - sum);
  __syncthreads();
#pragma unroll
  for (int q2 = 0; q2 < 8; q2++) { int o2 = excl + loc[q2]; off[base + q2] = o2; cnt[base + q2] = o2; }
  if (tid == 0) off[SLOTS] = NS;
  __syncthreads();
  for (int i2 = tid; i2 < NS; i2 += 1024) {
    int sl = idx[i2];
    int pos = atomicAdd(&cnt[sl], 1);
    slotA[pos] = sl; siteA[pos] = i2;
  }
}

// ---------------- K_main: logits -> softmax -> forward cumsum CHp ONLY ----------------
// Everything downstream derives from CHp: M[j] = CH[j]-CH[j-1], cv_L[j] = 1-CH[j-1], cv_H[j] = CH[j].
__global__ void __launch_bounds__(1024) k_main(const float* __restrict__ u,
    const float* __restrict__ A, const float* __restrict__ P,
    const float* __restrict__ v, const float* __restrict__ B, const float* __restrict__ Q,
    const float* __restrict__ lnb, const float* __restrict__ Wo, const float* __restrict__ bo,
    float* __restrict__ CHp) {
  int j = threadIdx.x;
  int lane = j & 63, wv = j >> 6;
  __shared__ float redB[16 * 16];  // [row][wave] wave sums
  float4 vv[8];
  const float4* vp = (const float4*)(v + j * HH2);
#pragma unroll
  for (int q = 0; q < 8; q++) vv[q] = vp[q];
  float Bj = B[j], Qj = Q[j];
  float C = bo[0];
#pragma unroll
  for (int k = 0; k < HH2; k++) C = fmaf(lnb[k], Wo[k], C);
  int row0 = blockIdx.x * 16;

  float incl[16];
#pragma unroll
  for (int rr = 0; rr < 16; rr++) {
    int i = row0 + rr;
    const float4* up = (const float4*)(u + i * HH2);
    float dot = 0.f;
#pragma unroll
    for (int q = 0; q < 8; q++) {
      float4 u4 = up[q];
      dot = fmaf(u4.x, vv[q].x, dot);
      dot = fmaf(u4.y, vv[q].y, dot);
      dot = fmaf(u4.z, vv[q].z, dot);
      dot = fmaf(u4.w, vv[q].w, dot);
    }
    float var = P[i] + Qj + dot * 0.0625f;   // P + Q + 2*dot/32
    float lg = rsqrtf(var + LNEPS) * (A[i] + Bj) + C;
    float ee = __expf(lg);
    float ic = ee;
#pragma unroll
    for (int o = 1; o < 64; o <<= 1) { float tt = __shfl_up(ic, o); if (lane >= o) ic += tt; }
    if (lane == 63) redB[rr * 16 + wv] = ic;
    incl[rr] = ic;
  }
  __syncthreads();
#pragma unroll
  for (int rr = 0; rr < 16; rr++) {
    const float4* rb = (const float4*)(redB + rr * 16);
    float4 b0 = rb[0], b1 = rb[1], b2 = rb[2], b3 = rb[3];
    float w_[16] = {b0.x, b0.y, b0.z, b0.w, b1.x, b1.y, b1.z, b1.w,
                    b2.x, b2.y, b2.z, b2.w, b3.x, b3.y, b3.z, b3.w};
    float prev = 0.f, tot = 0.f;
#pragma unroll
    for (int w = 0; w < 16; w++) { tot += w_[w]; if (w < wv) prev += w_[w]; }
    float chE = prev + incl[rr];
    float rd = 1.0f / tot;
    CHp[(row0 + rr) * NCC + j] = chE * rd;   // forward inclusive cumsum (last col == 1.0)
  }
}

// ---------------- K_band: BOTH bands, one launch, 2048 blocks (R2 geometry) ----------------
// band 0 (L): reads CH row (+ left neighbor, same cacheline), PURE-WRITES out = M * EL_chunklocal.
// band 1 (H): reads CH row, PURE-WRITES EHb = EH_chunklocal.  Independent outputs -> no RMW chain.
// Both write chunk-total products to TT[band][seq*8+chunk][col].
__global__ void __launch_bounds__(256) k_band(
    const float* __restrict__ CHp,
    const int* __restrict__ offl, const int* __restrict__ slotl, const int* __restrict__ sitel,
    const int* __restrict__ offh, const int* __restrict__ sloth, const int* __restrict__ siteh,
    float* __restrict__ outL, float* __restrict__ EHb, float* __restrict__ TT) {
  int band = blockIdx.y >> 3;          // 0 = lower, 1 = higher
  int chunk = blockIdx.y & 7;
  int seq = blockIdx.z;
  int tid = threadIdx.x;
  int j = blockIdx.x * 256 + tid;
  const int* off = band ? offh : offl;
  const int* slA = band ? sloth : slotl;
  const int* siA = band ? siteh : sitel;
  int slot0 = seq * SLEN + chunk * 32;
  int s0 = off[slot0];
  int n = off[slot0 + 32] - s0;
  size_t trow = ((size_t)band * 256 + seq * 8 + chunk) * NCC + j;
  if (n <= 0) { TT[trow] = 1.0f; return; }   // empty chunk: product of 32 unit factors
  if (n > MAXCH) n = MAXCH;
  __shared__ int ss[MAXCH];
  __shared__ int sl[MAXCH];
  for (int i = tid; i < n; i += 256) { ss[i] = siA[s0 + i]; sl[i] = slA[s0 + i]; }
  __syncthreads();

  const int T = 32;                    // covers n<=32; all loads issued before any store
  float r = 1.f, z = 0.f;
  int prev = -1;
  if (band == 0) {
    // ---- lower band ----
    float ch[T], cm[T];
#pragma unroll
    for (int k = 0; k < T; k++) {
      int kk = k < n ? k : n - 1;
      const float* rp = CHp + (size_t)ss[kk] * NCC + j;
      ch[k] = *rp;
      cm[k] = (j == 0) ? 0.f : rp[-1];   // same cacheline as ch[k]
    }
#pragma unroll
    for (int k = 0; k < T; k++) {
      if (k < n) {
        int slot = sl[k];
        if (slot != prev) {              // block-uniform branch (sl in LDS)
          if (prev >= 0) { r *= fmaxf(1.f - z, 0.f); z = 0.f; }
          prev = slot;
        }
        outL[(size_t)ss[k] * NCC + j] = (ch[k] - cm[k]) * r;  // M * EL
        z += 1.f - cm[k];                // cv_L = 1 - CH[j-1]
      }
    }
    for (int k = T; k < n; k++) {        // rare tail (n > 32)
      const float* rp = CHp + (size_t)ss[k] * NCC + j;
      float c = *rp, cmv = (j == 0) ? 0.f : rp[-1];
      int slot = sl[k];
      if (slot != prev) {
        if (prev >= 0) { r *= fmaxf(1.f - z, 0.f); z = 0.f; }
        prev = slot;
      }
      outL[(size_t)ss[k] * NCC + j] = (c - cmv) * r;
      z += 1.f - cmv;
    }
  } else {
    // ---- higher band ----
    float ch[T];
#pragma unroll
    for (int k = 0; k < T; k++) {
      int kk = k < n ? k : n - 1;
      ch[k] = CHp[(size_t)ss[kk] * NCC + j];
    }
#pragma unroll
    for (int k = 0; k < T; k++) {
      if (k < n) {
        int slot = sl[k];
        if (slot != prev) {
          if (prev >= 0) { r *= fmaxf(1.f - z, 0.f); z = 0.f; }
          prev = slot;
        }
        EHb[(size_t)ss[k] * NCC + j] = r;  // EH
        z += ch[k];                        // cv_H = CH[j]
      }
    }
    for (int k = T; k < n; k++) {          // rare tail
      float c = CHp[(size_t)ss[k] * NCC + j];
      int slot = sl[k];
      if (slot != prev) {
        if (prev >= 0) { r *= fmaxf(1.f - z, 0.f); z = 0.f; }
        prev = slot;
      }
      EHb[(size_t)ss[k] * NCC + j] = r;
      z += c;
    }
  }
  r *= fmaxf(1.f - z, 0.f);              // close the last occupied slot
  TT[trow] = r;                          // chunk total (empty trailing slots contribute 1)
}

// ---------------- K_final: out = (M*EL) * EH * PL * PH; chunk prefix folded in on the fly ----------------
// chunk index (idx>>5)&7 is block-uniform per site; raw TT rows (2 MiB total) are L2-resident,
// so the <=7 extra float4 reads per site are cheap. Product order matches the old k_prefix exactly.
__global__ void __launch_bounds__(256) k_final(
    float* __restrict__ out, const float* __restrict__ EHb, const float* __restrict__ TT,
    const int* __restrict__ idxl, const int* __restrict__ idxh) {
  int j = threadIdx.x * 4;
  int s0 = blockIdx.x * 8;
  const float* TTH = TT + (size_t)256 * NCC;
  for (int k = 0; k < 8; k++) {
    int s = s0 + k;
    int il = idxl[s] >> 5;               // seqL*8+chunkL  (0..255)
    int ih = idxh[s] >> 5;
    int cl = il & 7, chh = ih & 7;
    const float* tl = TT  + (size_t)(il - cl) * NCC + j;
    const float* th = TTH + (size_t)(ih - chh) * NCC + j;
    float4 pl = make_float4(1.f, 1.f, 1.f, 1.f);
    for (int c = 0; c < cl; c++) {       // uniform trip count per site
      float4 t = *(const float4*)(tl + (size_t)c * NCC);
      pl.x *= t.x; pl.y *= t.y; pl.z *= t.z; pl.w *= t.w;
    }
    float4 ph = make_float4(1.f, 1.f, 1.f, 1.f);
    for (int c = 0; c < chh; c++) {
      float4 t = *(const float4*)(th + (size_t)c * NCC);
      ph.x *= t.x; ph.y *= t.y; ph.z *= t.z; ph.w *= t.w;
    }
    size_t bofs = (size_t)s * NCC + j;
    float4 m  = *(const float4*)(out + bofs);
    float4 eh = *(const float4*)(EHb + bofs);
    float4 o;
    o.x = m.x * eh.x * pl.x * ph.x;
    o.y = m.y * eh.y * pl.y * ph.y;
    o.z = m.z * eh.z * pl.z * ph.z;
    o.w = m.w * eh.w * pl.w * ph.w;
    *(float4*)(out + bofs) = o;
  }
}

extern "C" void kernel_launch(void* const* d_in, const int* in_sizes, int n_in,
                              void* d_out, int out_size, void* d_ws, size_t ws_size,
                              hipStream_t stream) {
  const float* sites = (const float*)d_in[0];
  const float* cons  = (const float*)d_in[1];
  const int* idxl = (const int*)d_in[2];
  const int* idxh = (const int*)d_in[3];
  const float* Ws = (const float*)d_in[4];
  const float* bs = (const float*)d_in[5];
  const float* Wc = (const float*)d_in[6];
  const float* bc = (const float*)d_in[7];
  const float* Wd = (const float*)d_in[8];
  const float* bd = (const float*)d_in[9];
  const float* lng = (const float*)d_in[10];
  const float* lnb = (const float*)d_in[11];
  const float* Wo = (const float*)d_in[12];
  const float* bo = (const float*)d_in[13];

  char* wsb = (char*)d_ws;
  size_t o = 0;
  auto alloc = [&](size_t bytes) { char* p = wsb + o; o += (bytes + 15) & ~(size_t)15; return p; };
  float* u   = (float*)alloc((size_t)NS * HH2 * 4);
  float* A   = (float*)alloc((size_t)NS * 4);
  float* P   = (float*)alloc((size_t)NS * 4);
  float* v   = (float*)alloc((size_t)NCC * HH2 * 4);
  float* B   = (float*)alloc((size_t)NCC * 4);
  float* Q   = (float*)alloc((size_t)NCC * 4);
  float* CHp = (float*)alloc((size_t)NS * NCC * 4);
  float* EHb = (float*)alloc((size_t)NS * NCC * 4);
  float* TT  = (float*)alloc((size_t)2 * 256 * NCC * 4);   // [band][seq*8+chunk][col], RAW chunk totals
  int* offl  = (int*)alloc((SLOTS + 1) * 4);
  int* slotl = (int*)alloc(NS * 4);
  int* sitel = (int*)alloc(NS * 4);
  int* offh  = (int*)alloc((SLOTS + 1) * 4);
  int* sloth = (int*)alloc(NS * 4);
  int* siteh = (int*)alloc(NS * 4);

  k_setup<<<22, 1024, 0, stream>>>(sites, cons, Ws, bs, Wc, bc, Wd, bd, lng, Wo,
                                   u, A, P, v, B, Q,
                                   idxl, idxh, offl, slotl, sitel, offh, sloth, siteh);
  k_main<<<NS / 16, 1024, 0, stream>>>(u, A, P, v, B, Q, lnb, Wo, bo, CHp);
  k_band<<<dim3(4, 16, NSEQ), 256, 0, stream>>>(CHp,
                                                offl, slotl, sitel, offh, sloth, siteh,
                                                (float*)d_out, EHb, TT);
  k_final<<<NS / 8, 256, 0, stream>>>((float*)d_out, EHb, TT, idxl, idxh);
}